// Round 2
// baseline (1082.064 us; speedup 1.0000x reference)
//
#include <hip/hip_runtime.h>
#include <hip/hip_bf16.h>

// TimeLSTM fused persistent kernel for MI355X (gfx950).
// B=2048, T=512, D=24, H=100, O=2.
// One block = 8 batch rows for all 512 steps. Stationary fused weight matrix
// Bmat[128][512] = [[W_all;U_all;b_all+b_u;0] | [W_d;0;b_d;0]] held as MFMA
// B-fragments in registers. Per step: A=[h|x_t|1|0] (gates) / [c|0|1|0] (decay),
// 16x16x32 bf16 MFMA -> preacts in LDS -> thread-local gate/cell update.
// Output is float32 (reference returns f32; harness reads f32).

typedef __attribute__((ext_vector_type(8))) short bf16x8;
typedef __attribute__((ext_vector_type(4))) float f32x4;

#define B_SZ 2048
#define T_SZ 512
#define D_SZ 24
#define H_SZ 100
#define O_SZ 2

__device__ __forceinline__ unsigned short f2bf(float v) {
    return __builtin_bit_cast(unsigned short, __float2bfloat16(v));
}
__device__ __forceinline__ float sigm(float x) { return 1.0f / (1.0f + __expf(-x)); }
__device__ __forceinline__ float tanh_(float x) { return 2.0f / (1.0f + __expf(-2.0f * x)) - 1.0f; }

__global__ __launch_bounds__(512, 2) void tlstm_kernel(
    const float* __restrict__ input_seq, const float* __restrict__ ts,
    const float* __restrict__ W_all, const float* __restrict__ b_all,
    const float* __restrict__ U_all, const float* __restrict__ b_u,
    const float* __restrict__ W_d,  const float* __restrict__ b_d,
    const float* __restrict__ W_lin, const float* __restrict__ b_lin,
    float* __restrict__ out)
{
    // hx/cx: [parity][16 rows][128 k-slots] bf16, XOR-swizzled within each row:
    //   ushort index = r*128 + (k ^ ((r&7)<<3))   (byte ^= (r&7)<<4)
    // logical slots: 0..99 = h (resp. c), 100..123 = x_t (resp. 0), 124 = 1.0 (bias), 125..127 = 0
    __shared__ unsigned short hx[2][16 * 128];
    __shared__ unsigned short cx[2][16 * 128];
    // preact staging: [col 0..511][row 0..7, padded to 12] f32. cols 0..399 gates, 400..499 decay.
    __shared__ float C_lds[512 * 12];
    __shared__ float hl[8][H_SZ];   // final h for the output head (f32)

    const int tid   = (int)threadIdx.x;
    const int lane  = tid & 63;
    const int wave  = tid >> 6;
    const int row16 = lane & 15;   // A-row / B-col within tile
    const int kgrp  = lane >> 4;   // k-group (8 contiguous k per lane)
    const int rowbase = (int)blockIdx.x * 8;

    // ---- prologue: init hx/cx patterns (bias slot = 1.0, everything else 0) ----
    for (int i = tid; i < 2 * 16 * 128; i += 512) {
        const int p = i >> 11;
        const int r = (i >> 7) & 15;
        const int k = i & 127;
        const unsigned short v = (r < 8 && k == 124) ? (unsigned short)0x3F80 : (unsigned short)0;
        const int idx = r * 128 + (k ^ ((r & 7) << 3));
        hx[p][idx] = v;
        cx[p][idx] = v;
    }

    // ---- gather stationary B fragments into registers (64 VGPR) ----
    // B-frag (gemm_bt style): lane holds col = row16 (within tile), k = kgrp*8 + e, contiguous e.
    bf16x8 Bf[4][4];
    #pragma unroll
    for (int t = 0; t < 4; ++t) {
        const int n = (wave * 4 + t) * 16 + row16;   // global output column 0..511
        #pragma unroll
        for (int g = 0; g < 4; ++g) {
            bf16x8 fr;
            #pragma unroll
            for (int e = 0; e < 8; ++e) {
                const int k = g * 32 + kgrp * 8 + e;
                float v = 0.0f;
                if (n < 400) {                       // gates: preact = h@W_all + x@U_all + (b_all+b_u)
                    if (k < 100)       v = W_all[k * 400 + n];
                    else if (k < 124)  v = U_all[(k - 100) * 400 + n];
                    else if (k == 124) v = b_all[n] + b_u[n];
                } else {                             // decay: preact = c@W_d + b_d
                    const int jd = n - 400;
                    if (jd < 100) {
                        if (k < 100)       v = W_d[k * 100 + jd];
                        else if (k == 124) v = b_d[jd];
                    }
                }
                fr[e] = (short)f2bf(v);
            }
            Bf[t][g] = fr;
        }
    }

    __syncthreads();  // hx/cx init visible before x[0] staging overwrites slots

    // stage x at t=0 into hx[0]
    if (tid < 192) {
        const int r = tid / 24, d = tid % 24;
        const float v = input_seq[((size_t)(rowbase + r) * T_SZ) * D_SZ + d];
        const int k = 100 + d;
        hx[0][r * 128 + (k ^ ((r & 7) << 3))] = f2bf(v);
    }

    // epilogue mapping: thread tid<400 owns column j for rows r0=tid/100 and r1=r0+4
    const bool ep = (tid < 400);
    const int j  = tid % 100;
    const int r0 = tid / 100;
    const int r1 = r0 + 4;
    const bool xs = (tid < 192);
    const int xr = tid / 24, xd = tid % 24;

    float c0 = 0.0f, c1 = 0.0f;   // thread-local cell state (f32 carry)

    __syncthreads();

    int par = 0;
    for (int s = 0; s < T_SZ; ++s) {
        // global prefetches (consumed after the mid-step barrier; latency hides under MFMA)
        float ts0 = 0.f, ts1 = 0.f, xv = 0.f;
        if (ep) {
            ts0 = ts[(size_t)(rowbase + r0) * T_SZ + s];
            ts1 = ts[(size_t)(rowbase + r1) * T_SZ + s];
        }
        if (xs) {
            const int s1 = (s + 1 < T_SZ) ? (s + 1) : s;
            xv = input_seq[((size_t)(rowbase + xr) * T_SZ + s1) * D_SZ + xd];
        }

        // ---- phase 1: A-frags + MFMA + preact staging ----
        const unsigned short* hp = hx[par];
        const unsigned short* cp = cx[par];
        bf16x8 ah[4], ac[4];
        #pragma unroll
        for (int g = 0; g < 4; ++g) {
            const int idx = row16 * 128 + ((g * 32 + kgrp * 8) ^ ((row16 & 7) << 3));
            ah[g] = *(const bf16x8*)(hp + idx);
            ac[g] = *(const bf16x8*)(cp + idx);
        }

        #pragma unroll
        for (int t = 0; t < 4; ++t) {
            const int tile = wave * 4 + t;
            f32x4 acc = {0.f, 0.f, 0.f, 0.f};
            if (tile < 25) {   // gates region uses A=[h|x|1|0]
                #pragma unroll
                for (int g = 0; g < 4; ++g)
                    acc = __builtin_amdgcn_mfma_f32_16x16x32_bf16(ah[g], Bf[t][g], acc, 0, 0, 0);
            } else {           // decay region uses A=[c|0|1|0]
                #pragma unroll
                for (int g = 0; g < 4; ++g)
                    acc = __builtin_amdgcn_mfma_f32_16x16x32_bf16(ac[g], Bf[t][g], acc, 0, 0, 0);
            }
            // D layout: col=lane&15, row=(lane>>4)*4+reg. Keep rows 0..7 only (lanes 0..31).
            if (lane < 32) {
                const int col = tile * 16 + row16;
                *(f32x4*)&C_lds[col * 12 + kgrp * 4] = acc;
            }
        }

        __syncthreads();

        // ---- phase 2: thread-local gate/cell/h update, publish h,c (bf16), stage x[s+1] ----
        const int pn = par ^ 1;
        unsigned short* hn = hx[pn];
        unsigned short* cn = cx[pn];

        if (ep) {
            const float pf0 = C_lds[(j      ) * 12 + r0];
            const float pi0 = C_lds[(j + 100) * 12 + r0];
            const float po0 = C_lds[(j + 200) * 12 + r0];
            const float pg0 = C_lds[(j + 300) * 12 + r0];
            const float pd0 = C_lds[(j + 400) * 12 + r0];
            const float pf1 = C_lds[(j      ) * 12 + r1];
            const float pi1 = C_lds[(j + 100) * 12 + r1];
            const float po1 = C_lds[(j + 200) * 12 + r1];
            const float pg1 = C_lds[(j + 300) * 12 + r1];
            const float pd1 = C_lds[(j + 400) * 12 + r1];

            // chunk order: f, i, o, c~ ; all sigmoid. c_s1 = tanh(decay preact).
            const float f0 = sigm(pf0), i0 = sigm(pi0), o0 = sigm(po0), g0 = sigm(pg0);
            const float cs0 = tanh_(pd0);
            const float ca0 = c0 + cs0 * (ts0 - 1.0f);     // (c - cs1) + cs1*t
            c0 = f0 * ca0 + i0 * g0;
            const float h0 = o0 * tanh_(c0);

            const float f1 = sigm(pf1), i1 = sigm(pi1), o1 = sigm(po1), g1 = sigm(pg1);
            const float cs1v = tanh_(pd1);
            const float ca1 = c1 + cs1v * (ts1 - 1.0f);
            c1 = f1 * ca1 + i1 * g1;
            const float h1 = o1 * tanh_(c1);

            const int i0x = r0 * 128 + (j ^ ((r0 & 7) << 3));
            const int i1x = r1 * 128 + (j ^ ((r1 & 7) << 3));
            hn[i0x] = f2bf(h0);  cn[i0x] = f2bf(c0);
            hn[i1x] = f2bf(h1);  cn[i1x] = f2bf(c1);

            if (s == T_SZ - 1) { hl[r0][j] = h0; hl[r1][j] = h1; }
        }
        if (xs) {
            const int k = 100 + xd;
            hn[xr * 128 + (k ^ ((xr & 7) << 3))] = f2bf(xv);
        }

        __syncthreads();
        par = pn;
    }

    // ---- output head: relu(h_last @ W_lin + b_lin), f32 out ----
    if (tid < 16) {
        const int r = tid >> 1, o = tid & 1;
        float acc = b_lin[o];
        #pragma unroll 4
        for (int k = 0; k < H_SZ; ++k)
            acc += hl[r][k] * W_lin[k * O_SZ + o];
        acc = acc > 0.f ? acc : 0.f;
        out[(size_t)(rowbase + r) * O_SZ + o] = acc;
    }
}

extern "C" void kernel_launch(void* const* d_in, const int* in_sizes, int n_in,
                              void* d_out, int out_size, void* d_ws, size_t ws_size,
                              hipStream_t stream) {
    const float* input_seq = (const float*)d_in[0];
    const float* ts_p      = (const float*)d_in[1];
    const float* W_all     = (const float*)d_in[2];
    const float* b_all     = (const float*)d_in[3];
    const float* U_all     = (const float*)d_in[4];
    const float* b_u       = (const float*)d_in[5];
    const float* W_d       = (const float*)d_in[6];
    const float* b_d       = (const float*)d_in[7];
    const float* W_lin     = (const float*)d_in[8];
    const float* b_lin     = (const float*)d_in[9];

    tlstm_kernel<<<dim3(B_SZ / 8), dim3(512), 0, stream>>>(
        input_seq, ts_p, W_all, b_all, U_all, b_u, W_d, b_d, W_lin, b_lin,
        (float*)d_out);
}